// Round 19
// baseline (58.281 us; speedup 1.0000x reference)
//
#include <hip/hip_runtime.h>
#include <hip/hip_bf16.h>

#define NN 16384
#define DD 64
#define NBI 32                 // 512-row bands
#define NUNITS 2112            // sum_I (128 - 4I), I=0..31
#define NBLK 512               // 2 blocks/CU (56.4 KB LDS)
#define NPOSB (NN/4)
#define SCREEN_T 0.49f         // hinge>0 needs gram > ~0.5-3e-5; margin 1e-2

constexpr float F_EPS_PD   = 1e-6f;
constexpr float F_EPS_NORM = 1e-6f;

using bf16x8 = __attribute__((ext_vector_type(8))) short;
using f32x4  = __attribute__((ext_vector_type(4))) float;
typedef __attribute__((address_space(1))) const unsigned int gu32_t;
typedef __attribute__((address_space(3))) unsigned int       lu32_t;

__device__ __forceinline__ float wave_sum_f(float v) {
    #pragma unroll
    for (int o = 32; o >= 1; o >>= 1) v += __shfl_xor(v, o);
    return v;
}

__device__ __forceinline__ int band_off(int I) { return 2 * I * (65 - I); }

// ---------------------------------------------------------------------------
// Kernel 0: label histogram -> ncomp = N + (N^2 - sum_c n_c^2), as float.
// Depends only on lab; also resets the finalize ticket. One block, ~1.5 us.
// ---------------------------------------------------------------------------
__global__ __launch_bounds__(1024) void hist_kernel(
    const int* __restrict__ lab, float* __restrict__ ncmp,
    unsigned int* __restrict__ done) {
    __shared__ unsigned int hist[4][1024];
    __shared__ unsigned long long scT[16];
    int t = threadIdx.x;
    int w = t >> 6, lane = t & 63;
    for (int i = t; i < 4096; i += 1024) hist[i >> 10][i & 1023] = 0u;
    __syncthreads();
    const int4* lab4 = (const int4*)lab;
    for (int i = t; i < NN / 4; i += 1024) {
        int4 v = lab4[i];
        atomicAdd(&hist[w & 3][v.x & 1023], 1u);
        atomicAdd(&hist[w & 3][v.y & 1023], 1u);
        atomicAdd(&hist[w & 3][v.z & 1023], 1u);
        atomicAdd(&hist[w & 3][v.w & 1023], 1u);
    }
    __syncthreads();
    unsigned long long sqc = 0;
    {
        unsigned long long h = (unsigned long long)hist[0][t & 1023]
                             + hist[1][t & 1023] + hist[2][t & 1023]
                             + hist[3][t & 1023];
        sqc = h * h;
    }
    #pragma unroll
    for (int o = 32; o >= 1; o >>= 1) sqc += __shfl_xor(sqc, o);
    if (lane == 0) scT[w] = sqc;
    __syncthreads();
    if (t == 0) {
        unsigned long long s2 = 0;
        #pragma unroll
        for (int i = 0; i < 16; ++i) s2 += scT[i];
        unsigned long long nneg = (unsigned long long)NN * NN - s2;
        ncmp[0] = (float)((unsigned long long)NN + nneg);
        *done = 0u;
    }
}

// ---------------------------------------------------------------------------
// Kernel 1 (R16-proven): per-row normalize + bf16 copy + packed {u,lab}/
// {vc,lab} + exact fp32 positive-pair loss -> posP partials. No atomics.
// ---------------------------------------------------------------------------
__global__ __launch_bounds__(256) void norm_kernel(
    const float* __restrict__ emb, const int* __restrict__ pidx,
    const int* __restrict__ lab, float2* __restrict__ up,
    float2* __restrict__ vcp, __hip_bfloat16* __restrict__ ebf,
    float* __restrict__ posP) {
    int w    = threadIdx.x >> 6;
    int row  = blockIdx.x * 4 + w;
    int lane = threadIdx.x & 63;
    int j    = pidx[row];
    float x  = emb[(size_t)row * DD + lane];
    float xj = emb[(size_t)j   * DD + lane];

    float n2  = wave_sum_f(x * x);
    float sx  = wave_sum_f(x);
    float n2j = wave_sum_f(xj * xj);
    float sxj = wave_sum_f(xj);
    float dot = wave_sum_f(x * xj);

    float m  = fmaxf(sqrtf(n2),  F_EPS_NORM);
    float mj = fmaxf(sqrtf(n2j), F_EPS_NORM);
    ebf[(size_t)row * DD + lane] = __float2bfloat16(x / m);

    __shared__ float spos[4];
    if (lane == 0) {
        float sq  = n2 / (m * m);
        float sqj = n2j / (mj * mj);
        float s   = sx / m;
        float sj  = sxj / mj;
        float g   = dot / (m * mj);
        float lf  = (float)lab[row];
        up[row]  = make_float2(sq + 2.0f * F_EPS_PD * s, lf);
        vcp[row] = make_float2(
            sq - 2.0f * F_EPS_PD * s + (float)DD * F_EPS_PD * F_EPS_PD, lf);
        float d2p = sq + sqj - 2.0f * g + 2.0f * F_EPS_PD * (s - sj)
                  + (float)DD * F_EPS_PD * F_EPS_PD;
        spos[w] = fmaxf(d2p, 0.0f);
    }
    __syncthreads();
    if (threadIdx.x == 0)
        posP[blockIdx.x] = spos[0] + spos[1] + spos[2] + spos[3];
}

// ---------------------------------------------------------------------------
// Stage one (B tile 16 KB + vcp slice 1 KB) into a ring slot. 3 ops per wave
// (uniform -> exact vmcnt counts). B source XOR-preswizzled (both-sides rule).
// ---------------------------------------------------------------------------
__device__ __forceinline__ void stage_tile(const short* ebf, const float2* vcp,
                                           int tile, short* slotB, float2* slotV,
                                           int w, int lane) {
    const short* tbase = ebf + (size_t)tile * (128 * DD);
    int rlo = lane >> 3;
    int g   = (lane & 7) ^ rlo;
    #pragma unroll
    for (int q = 0; q < 2; ++q) {
        int m = w * 2 + q;
        __builtin_amdgcn_global_load_lds(
            (gu32_t*)(const void*)(tbase + (size_t)(8 * m + rlo) * DD + g * 8),
            (lu32_t*)(void*)(slotB + m * 512), 16, 0, 0);
    }
    __builtin_amdgcn_global_load_lds(
        (gu32_t*)(const void*)(vcp + (size_t)tile * 128 + lane * 2),
        (lu32_t*)(void*)slotV, 16, 0, 0);
}

// ---------------------------------------------------------------------------
// Kernel 2: R16 champion core (counted-vmcnt 3-slot ring, 2-deep prefetch,
// quarter-tile register pipeline under (512,2), zero vmem in compute) with
// two R19 deltas: (a) s_setprio REMOVED (m190: setprio hurts lockstep GEMM);
// (b) LIGHT finalize tail (R18-proven ticket): last block sums negP+posP and
// divides by precomputed ncomp. Heavy histogram moved to hist_kernel.
// ---------------------------------------------------------------------------
#define LOADQ(B, t0_)                                                          \
    do {                                                                       \
        const short* r0_ = lb + ((t0_) * 16 + lrow) * 64;                      \
        const short* r1_ = lb + (((t0_) + 1) * 16 + lrow) * 64;                \
        B[0][0] = *(const bf16x8*)(r0_ + c0s);                                 \
        B[0][1] = *(const bf16x8*)(r0_ + c1s);                                 \
        B[1][0] = *(const bf16x8*)(r1_ + c0s);                                 \
        B[1][1] = *(const bf16x8*)(r1_ + c1s);                                 \
    } while (0)

#define COMPQ(B, t0_)                                                          \
    do {                                                                       \
        _Pragma("unroll")                                                      \
        for (int tt_ = 0; tt_ < 2; ++tt_) {                                    \
            f32x4 c4[4];                                                       \
            _Pragma("unroll")                                                  \
            for (int s_ = 0; s_ < 4; ++s_) {                                   \
                f32x4 z_ = {0.f, 0.f, 0.f, 0.f};                               \
                z_ = __builtin_amdgcn_mfma_f32_16x16x32_bf16(a[s_][0], B[tt_][0], z_, 0, 0, 0); \
                z_ = __builtin_amdgcn_mfma_f32_16x16x32_bf16(a[s_][1], B[tt_][1], z_, 0, 0, 0); \
                c4[s_] = z_;                                                   \
            }                                                                  \
            float m0_ = fmaxf(fmaxf(c4[0][0], c4[0][1]), fmaxf(c4[0][2], c4[0][3])); \
            float m1_ = fmaxf(fmaxf(c4[1][0], c4[1][1]), fmaxf(c4[1][2], c4[1][3])); \
            float m2_ = fmaxf(fmaxf(c4[2][0], c4[2][1]), fmaxf(c4[2][2], c4[2][3])); \
            float m3_ = fmaxf(fmaxf(c4[3][0], c4[3][1]), fmaxf(c4[3][2], c4[3][3])); \
            float mx_ = fmaxf(fmaxf(m0_, m1_), fmaxf(m2_, m3_));               \
            if (__any(mx_ > SCREEN_T)) {            /* rare; LDS-only path */  \
                float2 vl_ = lv[((t0_) + tt_) * 16 + lrow];                    \
                _Pragma("unroll")                                              \
                for (int s_ = 0; s_ < 4; ++s_) {                               \
                    _Pragma("unroll")                                          \
                    for (int r_ = 0; r_ < 4; ++r_) {                           \
                        float2 ul_ = uband[w * 64 + 16 * s_ + lkh * 4 + r_];   \
                        float d2_ = fmaf(-2.0f, c4[s_][r_], ul_.x + vl_.x);    \
                        float d_  = sqrtf(fmaxf(d2_, 1e-12f));                 \
                        float h_  = fmaxf(1.0f - d_, 0.0f);                    \
                        if (ul_.y != vl_.y) hp = fmaf(h_, h_, hp);             \
                    }                                                          \
                }                                                              \
            }                                                                  \
        }                                                                      \
    } while (0)

__global__ __launch_bounds__(512, 2) void pair_kernel(
    const short* __restrict__ ebf, const float2* __restrict__ up,
    const float2* __restrict__ vcp, const float* __restrict__ posP,
    float* __restrict__ negP, const float* __restrict__ ncmp,
    unsigned int* done, float* __restrict__ out) {
    __shared__ short  ringB[3][8192];   // 3 x 16 KB B tiles (swizzled)
    __shared__ float2 ringV[3][128];    // 3 x 1 KB {vc,lab} slices
    __shared__ float2 uband[512];       // band {u,lab}, staged per segment
    __shared__ float  sred[8];
    __shared__ float  spT[8], snT[8];
    __shared__ unsigned int isLast;
    int tid  = threadIdx.x;
    int w    = tid >> 6;
    int lane = tid & 63;
    int lrow = lane & 15, lkh = lane >> 4;
    int c0s  = ((lkh)     ^ (lrow & 7)) * 8;   // swizzled K[0:32) chunk
    int c1s  = ((lkh + 4) ^ (lrow & 7)) * 8;   // swizzled K[32:64) chunk

    int ks = (int)(((long long)blockIdx.x * NUNITS) / NBLK);
    int ke = (int)(((long long)(blockIdx.x + 1) * NUNITS) / NBLK);

    // decode ks -> band I
    int I = (int)((65.0f - sqrtf(4225.0f - 2.0f * (float)ks)) * 0.5f);
    I = I < 0 ? 0 : (I > NBI - 1 ? NBI - 1 : I);
    while (band_off(I) > ks) --I;
    while (I < NBI - 1 && band_off(I + 1) <= ks) ++I;

    float hacc = 0.0f;
    int u0 = ks;
    while (u0 < ke) {
        int bend = band_off(I + 1);
        int n    = (ke < bend ? ke : bend) - u0;
        int tj0  = 4 * I + (u0 - band_off(I));
        int rowbase = I * 512 + w * 64;
        int rt      = 4 * I + (w >> 1);

        // --- segment prologue: A frags, u-band stage, prime 2 tiles ---
        bf16x8 a[4][2];
        #pragma unroll
        for (int s = 0; s < 4; ++s) {
            const short* ab = ebf + (size_t)(rowbase + 16 * s + lrow) * DD + lkh * 8;
            a[s][0] = *(const bf16x8*)(ab);
            a[s][1] = *(const bf16x8*)(ab + 32);
        }
        if (w < 4)
            __builtin_amdgcn_global_load_lds(
                (gu32_t*)(const void*)(up + (size_t)I * 512 + w * 128 + lane * 2),
                (lu32_t*)(void*)(uband + w * 128), 16, 0, 0);
        stage_tile(ebf, vcp, tj0, &ringB[0][0], &ringV[0][0], w, lane);
        if (n > 1)
            stage_tile(ebf, vcp, tj0 + 1, &ringB[1][0], &ringV[1][0], w, lane);

        int sl = 0;                        // ring slot of tile k
        for (int k = 0; k < n; ++k) {
            if (k + 1 < n) asm volatile("s_waitcnt vmcnt(3)" ::: "memory");
            else           asm volatile("s_waitcnt vmcnt(0)" ::: "memory");
            __builtin_amdgcn_s_barrier();
            __builtin_amdgcn_sched_barrier(0);
            int sl2 = (sl >= 1) ? sl - 1 : 2;     // slot of tile k+2
            if (k + 2 < n)
                stage_tile(ebf, vcp, tj0 + k + 2, &ringB[sl2][0], &ringV[sl2][0],
                           w, lane);

            int tj = tj0 + k;
            float wgt = (tj == rt) ? 1.0f : ((tj > rt) ? 2.0f : 0.0f);
            if (wgt != 0.0f) {
                const short*  lb = &ringB[sl][0];
                const float2* lv = &ringV[sl][0];
                float hp = 0.0f;
                bf16x8 Q0[2][2], Q1[2][2];
                // quarter-pipelined: reads of q+1 issue before compute of q
                LOADQ(Q0, 0);
                LOADQ(Q1, 2);
                COMPQ(Q0, 0);
                LOADQ(Q0, 4);
                COMPQ(Q1, 2);
                LOADQ(Q1, 6);
                COMPQ(Q0, 4);
                COMPQ(Q1, 6);
                hacc = fmaf(wgt, hp, hacc);
            }
            sl = (sl + 1 == 3) ? 0 : sl + 1;
        }
        __builtin_amdgcn_s_barrier();      // protect ring/uband reuse
        __builtin_amdgcn_sched_barrier(0);
        u0 += n;
        ++I;
    }

    hacc = wave_sum_f(hacc);
    if (lane == 0) sred[w] = hacc;
    __syncthreads();
    if (tid == 0) {
        float tn = 0.f;
        #pragma unroll
        for (int i = 0; i < 8; ++i) tn += sred[i];
        negP[blockIdx.x] = tn;
        __threadfence();
        unsigned int prev = __hip_atomic_fetch_add(done, 1u, __ATOMIC_ACQ_REL,
                                                   __HIP_MEMORY_SCOPE_AGENT);
        isLast = (prev == NBLK - 1) ? 1u : 0u;
    }
    __syncthreads();

    // ---- LIGHT finalize (last block only): sum posP (4096) + negP (512) ----
    if (isLast) {
        float ps = 0.f;
        for (int i = tid; i < NPOSB; i += 512) ps += posP[i];
        float ns = negP[tid];              // NBLK == 512 == blockDim
        ps = wave_sum_f(ps);
        ns = wave_sum_f(ns);
        if (lane == 0) { spT[w] = ps; snT[w] = ns; }
        __syncthreads();
        if (tid == 0) {
            float pos = 0.f, neg = 0.f;
            #pragma unroll
            for (int i = 0; i < 8; ++i) { pos += spT[i]; neg += snT[i]; }
            out[0] = (pos + neg) / ncmp[0];
        }
    }
}

// ---------------------------------------------------------------------------
// ws layout (bytes):
//   up   @ 0        : 131072  (float2[16384]: {u, label})
//   vcp  @ 131072   : 131072  (float2[16384]: {vc, label})
//   ebf  @ 262144   : 2097152
//   posP @ 2359296  : 16384   (NPOSB floats)
//   negP @ 2375680  : 2048    (NBLK=512 floats)
//   done @ 2377728  : 4       (ticket; reset by hist_kernel each call)
//   ncmp @ 2377732  : 4       (float n_comparisons, written by hist_kernel)
//   total 2377736
// ---------------------------------------------------------------------------
extern "C" void kernel_launch(void* const* d_in, const int* in_sizes, int n_in,
                              void* d_out, int out_size, void* d_ws, size_t ws_size,
                              hipStream_t stream) {
    const float* emb = (const float*)d_in[0];
    const int* lab   = (const int*)d_in[1];
    const int* pidx  = (const int*)d_in[2];
    float* out = (float*)d_out;
    char* ws = (char*)d_ws;
    float2*         up   = (float2*)(ws);
    float2*         vcp  = (float2*)(ws + 131072);
    __hip_bfloat16* ebf  = (__hip_bfloat16*)(ws + 262144);
    float*          posP = (float*)(ws + 2359296);
    float*          negP = (float*)(ws + 2375680);
    unsigned int*   done = (unsigned int*)(ws + 2377728);
    float*          ncmp = (float*)(ws + 2377732);

    hist_kernel<<<1, 1024, 0, stream>>>(lab, ncmp, done);
    norm_kernel<<<NPOSB, 256, 0, stream>>>(emb, pidx, lab, up, vcp, ebf, posP);
    pair_kernel<<<NBLK, 512, 0, stream>>>((const short*)ebf, up, vcp,
                                          posP, negP, ncmp, done, out);
}

// Round 20
// 53.376 us; speedup vs baseline: 1.0919x; 1.0919x over previous
//
#include <hip/hip_runtime.h>
#include <hip/hip_bf16.h>

#define NN 16384
#define DD 64
#define NBI 32                 // 512-row bands
#define NUNITS 2112            // sum_I (128 - 4I), I=0..31
#define NBLK 512               // 2 blocks/CU (56.4 KB LDS)
#define NPOSB (NN/4)
#define SCREEN_T 0.49f         // hinge>0 needs gram > ~0.5-3e-5; margin 1e-2

constexpr float F_EPS_PD   = 1e-6f;
constexpr float F_EPS_NORM = 1e-6f;

using bf16x8 = __attribute__((ext_vector_type(8))) short;
using f32x4  = __attribute__((ext_vector_type(4))) float;
typedef __attribute__((address_space(1))) const unsigned int gu32_t;
typedef __attribute__((address_space(3))) unsigned int       lu32_t;

__device__ __forceinline__ float wave_sum_f(float v) {
    #pragma unroll
    for (int o = 32; o >= 1; o >>= 1) v += __shfl_xor(v, o);
    return v;
}

__device__ __forceinline__ int band_off(int I) { return 2 * I * (65 - I); }

// ---------------------------------------------------------------------------
// Kernel 1: per-row normalize + bf16 copy + packed {u,lab}/{vc,lab} + exact
// fp32 positive-pair loss.   d2(i,j) = u_i + vc_j - 2*gram(i,j)
// ---------------------------------------------------------------------------
__global__ __launch_bounds__(256) void norm_kernel(
    const float* __restrict__ emb, const int* __restrict__ pidx,
    const int* __restrict__ lab, float2* __restrict__ up,
    float2* __restrict__ vcp, __hip_bfloat16* __restrict__ ebf,
    float* __restrict__ posP) {
    int w    = threadIdx.x >> 6;
    int row  = blockIdx.x * 4 + w;
    int lane = threadIdx.x & 63;
    int j    = pidx[row];
    float x  = emb[(size_t)row * DD + lane];
    float xj = emb[(size_t)j   * DD + lane];

    float n2  = wave_sum_f(x * x);
    float sx  = wave_sum_f(x);
    float n2j = wave_sum_f(xj * xj);
    float sxj = wave_sum_f(xj);
    float dot = wave_sum_f(x * xj);

    float m  = fmaxf(sqrtf(n2),  F_EPS_NORM);
    float mj = fmaxf(sqrtf(n2j), F_EPS_NORM);
    ebf[(size_t)row * DD + lane] = __float2bfloat16(x / m);

    __shared__ float spos[4];
    if (lane == 0) {
        float sq  = n2 / (m * m);
        float sqj = n2j / (mj * mj);
        float s   = sx / m;
        float sj  = sxj / mj;
        float g   = dot / (m * mj);
        float lf  = (float)lab[row];
        up[row]  = make_float2(sq + 2.0f * F_EPS_PD * s, lf);
        vcp[row] = make_float2(
            sq - 2.0f * F_EPS_PD * s + (float)DD * F_EPS_PD * F_EPS_PD, lf);
        float d2p = sq + sqj - 2.0f * g + 2.0f * F_EPS_PD * (s - sj)
                  + (float)DD * F_EPS_PD * F_EPS_PD;
        spos[w] = fmaxf(d2p, 0.0f);
    }
    __syncthreads();
    if (threadIdx.x == 0)
        posP[blockIdx.x] = spos[0] + spos[1] + spos[2] + spos[3];
}

// ---------------------------------------------------------------------------
// Stage one (B tile 16 KB + vcp slice 1 KB) into a ring slot. 3 ops per wave
// (uniform -> exact vmcnt counts). B source XOR-preswizzled (both-sides rule).
// ---------------------------------------------------------------------------
__device__ __forceinline__ void stage_tile(const short* ebf, const float2* vcp,
                                           int tile, short* slotB, float2* slotV,
                                           int w, int lane) {
    const short* tbase = ebf + (size_t)tile * (128 * DD);
    int rlo = lane >> 3;
    int g   = (lane & 7) ^ rlo;
    #pragma unroll
    for (int q = 0; q < 2; ++q) {
        int m = w * 2 + q;
        __builtin_amdgcn_global_load_lds(
            (gu32_t*)(const void*)(tbase + (size_t)(8 * m + rlo) * DD + g * 8),
            (lu32_t*)(void*)(slotB + m * 512), 16, 0, 0);
    }
    __builtin_amdgcn_global_load_lds(
        (gu32_t*)(const void*)(vcp + (size_t)tile * 128 + lane * 2),
        (lu32_t*)(void*)slotV, 16, 0, 0);
}

// ---------------------------------------------------------------------------
// Kernel 2: R16 champion core (counted-vmcnt 3-slot ring, 2-deep prefetch,
// quarter-tile register pipeline under (512,2) VGPR headroom, zero vmem in
// compute). R20 delta vs R16: s_setprio removed (R18/R19 A/B: -0.7us; m190:
// setprio null-to-negative on lockstep GEMM). NO in-kernel finalize tail —
// R18/R19 showed per-block threadfence/agent-RMW costs +8us vs a separate
// reduce dispatch (L2 writeback cache-maintenance on stragglers).
// ---------------------------------------------------------------------------
#define LOADQ(B, t0_)                                                          \
    do {                                                                       \
        const short* r0_ = lb + ((t0_) * 16 + lrow) * 64;                      \
        const short* r1_ = lb + (((t0_) + 1) * 16 + lrow) * 64;                \
        B[0][0] = *(const bf16x8*)(r0_ + c0s);                                 \
        B[0][1] = *(const bf16x8*)(r0_ + c1s);                                 \
        B[1][0] = *(const bf16x8*)(r1_ + c0s);                                 \
        B[1][1] = *(const bf16x8*)(r1_ + c1s);                                 \
    } while (0)

#define COMPQ(B, t0_)                                                          \
    do {                                                                       \
        _Pragma("unroll")                                                      \
        for (int tt_ = 0; tt_ < 2; ++tt_) {                                    \
            f32x4 c4[4];                                                       \
            _Pragma("unroll")                                                  \
            for (int s_ = 0; s_ < 4; ++s_) {                                   \
                f32x4 z_ = {0.f, 0.f, 0.f, 0.f};                               \
                z_ = __builtin_amdgcn_mfma_f32_16x16x32_bf16(a[s_][0], B[tt_][0], z_, 0, 0, 0); \
                z_ = __builtin_amdgcn_mfma_f32_16x16x32_bf16(a[s_][1], B[tt_][1], z_, 0, 0, 0); \
                c4[s_] = z_;                                                   \
            }                                                                  \
            float m0_ = fmaxf(fmaxf(c4[0][0], c4[0][1]), fmaxf(c4[0][2], c4[0][3])); \
            float m1_ = fmaxf(fmaxf(c4[1][0], c4[1][1]), fmaxf(c4[1][2], c4[1][3])); \
            float m2_ = fmaxf(fmaxf(c4[2][0], c4[2][1]), fmaxf(c4[2][2], c4[2][3])); \
            float m3_ = fmaxf(fmaxf(c4[3][0], c4[3][1]), fmaxf(c4[3][2], c4[3][3])); \
            float mx_ = fmaxf(fmaxf(m0_, m1_), fmaxf(m2_, m3_));               \
            if (__any(mx_ > SCREEN_T)) {            /* rare; LDS-only path */  \
                float2 vl_ = lv[((t0_) + tt_) * 16 + lrow];                    \
                _Pragma("unroll")                                              \
                for (int s_ = 0; s_ < 4; ++s_) {                               \
                    _Pragma("unroll")                                          \
                    for (int r_ = 0; r_ < 4; ++r_) {                           \
                        float2 ul_ = uband[w * 64 + 16 * s_ + lkh * 4 + r_];   \
                        float d2_ = fmaf(-2.0f, c4[s_][r_], ul_.x + vl_.x);    \
                        float d_  = sqrtf(fmaxf(d2_, 1e-12f));                 \
                        float h_  = fmaxf(1.0f - d_, 0.0f);                    \
                        if (ul_.y != vl_.y) hp = fmaf(h_, h_, hp);             \
                    }                                                          \
                }                                                              \
            }                                                                  \
        }                                                                      \
    } while (0)

__global__ __launch_bounds__(512, 2) void pair_kernel(
    const short* __restrict__ ebf, const float2* __restrict__ up,
    const float2* __restrict__ vcp, float* __restrict__ negP) {
    __shared__ short  ringB[3][8192];   // 3 x 16 KB B tiles (swizzled)
    __shared__ float2 ringV[3][128];    // 3 x 1 KB {vc,lab} slices
    __shared__ float2 uband[512];       // band {u,lab}, staged per segment
    __shared__ float  sred[8];
    int tid  = threadIdx.x;
    int w    = tid >> 6;
    int lane = tid & 63;
    int lrow = lane & 15, lkh = lane >> 4;
    int c0s  = ((lkh)     ^ (lrow & 7)) * 8;   // swizzled K[0:32) chunk
    int c1s  = ((lkh + 4) ^ (lrow & 7)) * 8;   // swizzled K[32:64) chunk

    int ks = (int)(((long long)blockIdx.x * NUNITS) / NBLK);
    int ke = (int)(((long long)(blockIdx.x + 1) * NUNITS) / NBLK);

    // decode ks -> band I
    int I = (int)((65.0f - sqrtf(4225.0f - 2.0f * (float)ks)) * 0.5f);
    I = I < 0 ? 0 : (I > NBI - 1 ? NBI - 1 : I);
    while (band_off(I) > ks) --I;
    while (I < NBI - 1 && band_off(I + 1) <= ks) ++I;

    float hacc = 0.0f;
    int u0 = ks;
    while (u0 < ke) {
        int bend = band_off(I + 1);
        int n    = (ke < bend ? ke : bend) - u0;
        int tj0  = 4 * I + (u0 - band_off(I));
        int rowbase = I * 512 + w * 64;
        int rt      = 4 * I + (w >> 1);

        // --- segment prologue: A frags, u-band stage, prime 2 tiles ---
        bf16x8 a[4][2];
        #pragma unroll
        for (int s = 0; s < 4; ++s) {
            const short* ab = ebf + (size_t)(rowbase + 16 * s + lrow) * DD + lkh * 8;
            a[s][0] = *(const bf16x8*)(ab);
            a[s][1] = *(const bf16x8*)(ab + 32);
        }
        if (w < 4)
            __builtin_amdgcn_global_load_lds(
                (gu32_t*)(const void*)(up + (size_t)I * 512 + w * 128 + lane * 2),
                (lu32_t*)(void*)(uband + w * 128), 16, 0, 0);
        stage_tile(ebf, vcp, tj0, &ringB[0][0], &ringV[0][0], w, lane);
        if (n > 1)
            stage_tile(ebf, vcp, tj0 + 1, &ringB[1][0], &ringV[1][0], w, lane);

        int sl = 0;                        // ring slot of tile k
        for (int k = 0; k < n; ++k) {
            if (k + 1 < n) asm volatile("s_waitcnt vmcnt(3)" ::: "memory");
            else           asm volatile("s_waitcnt vmcnt(0)" ::: "memory");
            __builtin_amdgcn_s_barrier();
            __builtin_amdgcn_sched_barrier(0);
            int sl2 = (sl >= 1) ? sl - 1 : 2;     // slot of tile k+2
            if (k + 2 < n)
                stage_tile(ebf, vcp, tj0 + k + 2, &ringB[sl2][0], &ringV[sl2][0],
                           w, lane);

            int tj = tj0 + k;
            float wgt = (tj == rt) ? 1.0f : ((tj > rt) ? 2.0f : 0.0f);
            if (wgt != 0.0f) {
                const short*  lb = &ringB[sl][0];
                const float2* lv = &ringV[sl][0];
                float hp = 0.0f;
                bf16x8 Q0[2][2], Q1[2][2];
                // quarter-pipelined: reads of q+1 issue before compute of q
                LOADQ(Q0, 0);
                LOADQ(Q1, 2);
                COMPQ(Q0, 0);
                LOADQ(Q0, 4);
                COMPQ(Q1, 2);
                LOADQ(Q1, 6);
                COMPQ(Q0, 4);
                COMPQ(Q1, 6);
                hacc = fmaf(wgt, hp, hacc);
            }
            sl = (sl + 1 == 3) ? 0 : sl + 1;
        }
        __builtin_amdgcn_s_barrier();      // protect ring/uband reuse
        __builtin_amdgcn_sched_barrier(0);
        u0 += n;
        ++I;
    }

    hacc = wave_sum_f(hacc);
    if (lane == 0) sred[w] = hacc;
    __syncthreads();
    if (tid == 0) {
        float tn = 0.f;
        #pragma unroll
        for (int i = 0; i < 8; ++i) tn += sred[i];
        negP[blockIdx.x] = tn;
    }
}

// ---------------------------------------------------------------------------
// Kernel 3: final reduction + 4-replica label histogram -> analytic negative
// count: n_neg = N^2 - sum_c n_c^2 ; n_comparisons = N + n_neg
// ---------------------------------------------------------------------------
__global__ __launch_bounds__(1024) void reduce_kernel(
    const float* __restrict__ posP, const float* __restrict__ negP,
    const int* __restrict__ lab, float* __restrict__ out) {
    __shared__ unsigned int hist[4][1024];
    int t = threadIdx.x;
    int w = t >> 6, lane = t & 63;
    for (int i = t; i < 4096; i += 1024) hist[i >> 10][i & 1023] = 0u;
    __syncthreads();
    const int4* lab4 = (const int4*)lab;
    for (int i = t; i < NN / 4; i += 1024) {
        int4 v = lab4[i];
        atomicAdd(&hist[w & 3][v.x & 1023], 1u);
        atomicAdd(&hist[w & 3][v.y & 1023], 1u);
        atomicAdd(&hist[w & 3][v.z & 1023], 1u);
        atomicAdd(&hist[w & 3][v.w & 1023], 1u);
    }
    __syncthreads();

    float ps = 0.f, ns = 0.f;
    unsigned long long sqc = 0u;
    const float4* posP4 = (const float4*)posP;
    for (int i = t; i < NPOSB / 4; i += 1024) {
        float4 v = posP4[i];
        ps += (v.x + v.y) + (v.z + v.w);
    }
    if (t < NBLK) ns = negP[t];
    {
        unsigned long long h = (unsigned long long)hist[0][t & 1023] + hist[1][t & 1023]
                             + hist[2][t & 1023] + hist[3][t & 1023];
        sqc = h * h;
    }

    ps = wave_sum_f(ps);
    ns = wave_sum_f(ns);
    #pragma unroll
    for (int o = 32; o >= 1; o >>= 1) sqc += __shfl_xor(sqc, o);

    __shared__ float sp[16], sn[16];
    __shared__ unsigned long long sc[16];
    if (lane == 0) { sp[w] = ps; sn[w] = ns; sc[w] = sqc; }
    __syncthreads();
    if (t == 0) {
        float pos = 0.f, neg = 0.f;
        unsigned long long s2 = 0;
        #pragma unroll
        for (int i = 0; i < 16; ++i) { pos += sp[i]; neg += sn[i]; s2 += sc[i]; }
        unsigned long long nneg = (unsigned long long)NN * NN - s2;
        float ncomp = (float)((unsigned long long)NN + nneg);
        out[0] = (pos + neg) / ncomp;
    }
}

// ---------------------------------------------------------------------------
// ws layout (bytes):
//   up   @ 0        : 131072  (float2[16384]: {u, label})
//   vcp  @ 131072   : 131072  (float2[16384]: {vc, label})
//   ebf  @ 262144   : 2097152
//   posP @ 2359296  : 16384   (NPOSB floats)
//   negP @ 2375680  : 2048    (NBLK=512 floats)
//   total 2377728
// ---------------------------------------------------------------------------
extern "C" void kernel_launch(void* const* d_in, const int* in_sizes, int n_in,
                              void* d_out, int out_size, void* d_ws, size_t ws_size,
                              hipStream_t stream) {
    const float* emb = (const float*)d_in[0];
    const int* lab   = (const int*)d_in[1];
    const int* pidx  = (const int*)d_in[2];
    float* out = (float*)d_out;
    char* ws = (char*)d_ws;
    float2*         up   = (float2*)(ws);
    float2*         vcp  = (float2*)(ws + 131072);
    __hip_bfloat16* ebf  = (__hip_bfloat16*)(ws + 262144);
    float*          posP = (float*)(ws + 2359296);
    float*          negP = (float*)(ws + 2375680);

    norm_kernel<<<NPOSB, 256, 0, stream>>>(emb, pidx, lab, up, vcp, ebf, posP);
    pair_kernel<<<NBLK, 512, 0, stream>>>((const short*)ebf, up, vcp, negP);
    reduce_kernel<<<1, 1024, 0, stream>>>(posP, negP, lab, out);
}

// Round 21
// 53.126 us; speedup vs baseline: 1.0970x; 1.0047x over previous
//
#include <hip/hip_runtime.h>
#include <hip/hip_bf16.h>

#define NN 16384
#define DD 64
#define NBI 32                 // 512-row bands
#define NUNITS 2112            // sum_I (128 - 4I), I=0..31
#define NBLK 512               // 2 blocks/CU (56.4 KB LDS)
#define NPOSB (NN/4)
#define SCREEN_T 0.49f         // hinge>0 needs gram > ~0.5-3e-5; margin 1e-2

constexpr float F_EPS_PD   = 1e-6f;
constexpr float F_EPS_NORM = 1e-6f;

using bf16x8 = __attribute__((ext_vector_type(8))) short;
using f32x4  = __attribute__((ext_vector_type(4))) float;
typedef __attribute__((address_space(1))) const unsigned int gu32_t;
typedef __attribute__((address_space(3))) unsigned int       lu32_t;

__device__ __forceinline__ float wave_sum_f(float v) {
    #pragma unroll
    for (int o = 32; o >= 1; o >>= 1) v += __shfl_xor(v, o);
    return v;
}

__device__ __forceinline__ int band_off(int I) { return 2 * I * (65 - I); }

// ---------------------------------------------------------------------------
// Kernel 1: per-row normalize + bf16 copy + packed {u,lab}/{vc,lab} + exact
// fp32 positive-pair loss.   d2(i,j) = u_i + vc_j - 2*gram(i,j)
// ---------------------------------------------------------------------------
__global__ __launch_bounds__(256) void norm_kernel(
    const float* __restrict__ emb, const int* __restrict__ pidx,
    const int* __restrict__ lab, float2* __restrict__ up,
    float2* __restrict__ vcp, __hip_bfloat16* __restrict__ ebf,
    float* __restrict__ posP) {
    int w    = threadIdx.x >> 6;
    int row  = blockIdx.x * 4 + w;
    int lane = threadIdx.x & 63;
    int j    = pidx[row];
    float x  = emb[(size_t)row * DD + lane];
    float xj = emb[(size_t)j   * DD + lane];

    float n2  = wave_sum_f(x * x);
    float sx  = wave_sum_f(x);
    float n2j = wave_sum_f(xj * xj);
    float sxj = wave_sum_f(xj);
    float dot = wave_sum_f(x * xj);

    float m  = fmaxf(sqrtf(n2),  F_EPS_NORM);
    float mj = fmaxf(sqrtf(n2j), F_EPS_NORM);
    ebf[(size_t)row * DD + lane] = __float2bfloat16(x / m);

    __shared__ float spos[4];
    if (lane == 0) {
        float sq  = n2 / (m * m);
        float sqj = n2j / (mj * mj);
        float s   = sx / m;
        float sj  = sxj / mj;
        float g   = dot / (m * mj);
        float lf  = (float)lab[row];
        up[row]  = make_float2(sq + 2.0f * F_EPS_PD * s, lf);
        vcp[row] = make_float2(
            sq - 2.0f * F_EPS_PD * s + (float)DD * F_EPS_PD * F_EPS_PD, lf);
        float d2p = sq + sqj - 2.0f * g + 2.0f * F_EPS_PD * (s - sj)
                  + (float)DD * F_EPS_PD * F_EPS_PD;
        spos[w] = fmaxf(d2p, 0.0f);
    }
    __syncthreads();
    if (threadIdx.x == 0)
        posP[blockIdx.x] = spos[0] + spos[1] + spos[2] + spos[3];
}

// ---------------------------------------------------------------------------
// Stage one (B tile 16 KB + vcp slice 1 KB) into a ring slot. 3 ops per wave
// (uniform -> exact vmcnt counts). B source XOR-preswizzled (both-sides rule).
// ---------------------------------------------------------------------------
__device__ __forceinline__ void stage_tile(const short* ebf, const float2* vcp,
                                           int tile, short* slotB, float2* slotV,
                                           int w, int lane) {
    const short* tbase = ebf + (size_t)tile * (128 * DD);
    int rlo = lane >> 3;
    int g   = (lane & 7) ^ rlo;
    #pragma unroll
    for (int q = 0; q < 2; ++q) {
        int m = w * 2 + q;
        __builtin_amdgcn_global_load_lds(
            (gu32_t*)(const void*)(tbase + (size_t)(8 * m + rlo) * DD + g * 8),
            (lu32_t*)(void*)(slotB + m * 512), 16, 0, 0);
    }
    __builtin_amdgcn_global_load_lds(
        (gu32_t*)(const void*)(vcp + (size_t)tile * 128 + lane * 2),
        (lu32_t*)(void*)slotV, 16, 0, 0);
}

// ---------------------------------------------------------------------------
// Kernel 2 (R21): R20 skeleton (counted-vmcnt 3-slot ring, 2-deep prefetch,
// zero vmem in compute, no setprio) with a 3-STAGE PER-T SOFTWARE PIPELINE:
//   steady step k:  load(t_{k+2}) || mfma(t_{k+1}) || screen(t_k)
// Named bufs BA/BB (B-frags) and CA/CB (accs) give every dependence a full
// step to resolve (ds_read->MFMA and MFMA->screen gaps = 1 step each).
// Interleave enforced per-step with counted sched_group_barrier (T19; m137:
// applied+safe, unlike mask-0 pinning). Needs (512,2)'s 128-VGPR budget —
// R9's null was at 60 VGPR where the pipeline couldn't materialize.
// ---------------------------------------------------------------------------
#define LD1(B, t_)                                                             \
    do {                                                                       \
        const short* r_ = lb + ((t_) * 16 + lrow) * 64;                        \
        B[0] = *(const bf16x8*)(r_ + c0s);                                     \
        B[1] = *(const bf16x8*)(r_ + c1s);                                     \
    } while (0)

#define MM1(C, B)                                                              \
    do {                                                                       \
        _Pragma("unroll")                                                      \
        for (int s_ = 0; s_ < 4; ++s_) {                                       \
            f32x4 z_ = {0.f, 0.f, 0.f, 0.f};                                   \
            z_ = __builtin_amdgcn_mfma_f32_16x16x32_bf16(a[s_][0], B[0], z_, 0, 0, 0); \
            z_ = __builtin_amdgcn_mfma_f32_16x16x32_bf16(a[s_][1], B[1], z_, 0, 0, 0); \
            C[s_] = z_;                                                        \
        }                                                                      \
    } while (0)

#define SC1(C, t_)                                                             \
    do {                                                                       \
        float m0_ = fmaxf(fmaxf(C[0][0], C[0][1]), fmaxf(C[0][2], C[0][3]));   \
        float m1_ = fmaxf(fmaxf(C[1][0], C[1][1]), fmaxf(C[1][2], C[1][3]));   \
        float m2_ = fmaxf(fmaxf(C[2][0], C[2][1]), fmaxf(C[2][2], C[2][3]));   \
        float m3_ = fmaxf(fmaxf(C[3][0], C[3][1]), fmaxf(C[3][2], C[3][3]));   \
        float mx_ = fmaxf(fmaxf(m0_, m1_), fmaxf(m2_, m3_));                   \
        if (__any(mx_ > SCREEN_T)) {            /* rare; LDS-only path */      \
            float2 vl_ = lv[(t_) * 16 + lrow];                                 \
            _Pragma("unroll")                                                  \
            for (int s_ = 0; s_ < 4; ++s_) {                                   \
                _Pragma("unroll")                                              \
                for (int r_ = 0; r_ < 4; ++r_) {                               \
                    float2 ul_ = uband[w * 64 + 16 * s_ + lkh * 4 + r_];       \
                    float d2_ = fmaf(-2.0f, C[s_][r_], ul_.x + vl_.x);         \
                    float d_  = sqrtf(fmaxf(d2_, 1e-12f));                     \
                    float h_  = fmaxf(1.0f - d_, 0.0f);                        \
                    if (ul_.y != vl_.y) hp = fmaf(h_, h_, hp);                 \
                }                                                              \
            }                                                                  \
        }                                                                      \
    } while (0)

// per-step scheduling hint: 2 ds_read, then 8 MFMA, then 16 VALU (screen)
#define SGB()                                                                  \
    do {                                                                       \
        __builtin_amdgcn_sched_group_barrier(0x100, 2, 0);                     \
        __builtin_amdgcn_sched_group_barrier(0x008, 8, 0);                     \
        __builtin_amdgcn_sched_group_barrier(0x002, 16, 0);                    \
    } while (0)

__global__ __launch_bounds__(512, 2) void pair_kernel(
    const short* __restrict__ ebf, const float2* __restrict__ up,
    const float2* __restrict__ vcp, float* __restrict__ negP) {
    __shared__ short  ringB[3][8192];   // 3 x 16 KB B tiles (swizzled)
    __shared__ float2 ringV[3][128];    // 3 x 1 KB {vc,lab} slices
    __shared__ float2 uband[512];       // band {u,lab}, staged per segment
    __shared__ float  sred[8];
    int tid  = threadIdx.x;
    int w    = tid >> 6;
    int lane = tid & 63;
    int lrow = lane & 15, lkh = lane >> 4;
    int c0s  = ((lkh)     ^ (lrow & 7)) * 8;   // swizzled K[0:32) chunk
    int c1s  = ((lkh + 4) ^ (lrow & 7)) * 8;   // swizzled K[32:64) chunk

    int ks = (int)(((long long)blockIdx.x * NUNITS) / NBLK);
    int ke = (int)(((long long)(blockIdx.x + 1) * NUNITS) / NBLK);

    // decode ks -> band I
    int I = (int)((65.0f - sqrtf(4225.0f - 2.0f * (float)ks)) * 0.5f);
    I = I < 0 ? 0 : (I > NBI - 1 ? NBI - 1 : I);
    while (band_off(I) > ks) --I;
    while (I < NBI - 1 && band_off(I + 1) <= ks) ++I;

    float hacc = 0.0f;
    int u0 = ks;
    while (u0 < ke) {
        int bend = band_off(I + 1);
        int n    = (ke < bend ? ke : bend) - u0;
        int tj0  = 4 * I + (u0 - band_off(I));
        int rowbase = I * 512 + w * 64;
        int rt      = 4 * I + (w >> 1);

        // --- segment prologue: A frags, u-band stage, prime 2 tiles ---
        bf16x8 a[4][2];
        #pragma unroll
        for (int s = 0; s < 4; ++s) {
            const short* ab = ebf + (size_t)(rowbase + 16 * s + lrow) * DD + lkh * 8;
            a[s][0] = *(const bf16x8*)(ab);
            a[s][1] = *(const bf16x8*)(ab + 32);
        }
        if (w < 4)
            __builtin_amdgcn_global_load_lds(
                (gu32_t*)(const void*)(up + (size_t)I * 512 + w * 128 + lane * 2),
                (lu32_t*)(void*)(uband + w * 128), 16, 0, 0);
        stage_tile(ebf, vcp, tj0, &ringB[0][0], &ringV[0][0], w, lane);
        if (n > 1)
            stage_tile(ebf, vcp, tj0 + 1, &ringB[1][0], &ringV[1][0], w, lane);

        int sl = 0;                        // ring slot of tile k
        for (int k = 0; k < n; ++k) {
            if (k + 1 < n) asm volatile("s_waitcnt vmcnt(3)" ::: "memory");
            else           asm volatile("s_waitcnt vmcnt(0)" ::: "memory");
            __builtin_amdgcn_s_barrier();
            __builtin_amdgcn_sched_barrier(0);
            int sl2 = (sl >= 1) ? sl - 1 : 2;     // slot of tile k+2
            if (k + 2 < n)
                stage_tile(ebf, vcp, tj0 + k + 2, &ringB[sl2][0], &ringV[sl2][0],
                           w, lane);

            int tj = tj0 + k;
            float wgt = (tj == rt) ? 1.0f : ((tj > rt) ? 2.0f : 0.0f);
            if (wgt != 0.0f) {
                const short*  lb = &ringB[sl][0];
                const float2* lv = &ringV[sl][0];
                float hp = 0.0f;
                bf16x8 BA[2], BB[2];
                f32x4 CA[4], CB[4];
                // 3-stage pipeline: load(t+2) || mfma(t+1) || screen(t)
                LD1(BA, 0);
                LD1(BB, 1); MM1(CA, BA);
                LD1(BA, 2); MM1(CB, BB); SC1(CA, 0); SGB();
                LD1(BB, 3); MM1(CA, BA); SC1(CB, 1); SGB();
                LD1(BA, 4); MM1(CB, BB); SC1(CA, 2); SGB();
                LD1(BB, 5); MM1(CA, BA); SC1(CB, 3); SGB();
                LD1(BA, 6); MM1(CB, BB); SC1(CA, 4); SGB();
                LD1(BB, 7); MM1(CA, BA); SC1(CB, 5); SGB();
                MM1(CB, BB); SC1(CA, 6);
                SC1(CB, 7);
                hacc = fmaf(wgt, hp, hacc);
            }
            sl = (sl + 1 == 3) ? 0 : sl + 1;
        }
        __builtin_amdgcn_s_barrier();      // protect ring/uband reuse
        __builtin_amdgcn_sched_barrier(0);
        u0 += n;
        ++I;
    }

    hacc = wave_sum_f(hacc);
    if (lane == 0) sred[w] = hacc;
    __syncthreads();
    if (tid == 0) {
        float tn = 0.f;
        #pragma unroll
        for (int i = 0; i < 8; ++i) tn += sred[i];
        negP[blockIdx.x] = tn;
    }
}

// ---------------------------------------------------------------------------
// Kernel 3: final reduction + 4-replica label histogram -> analytic negative
// count: n_neg = N^2 - sum_c n_c^2 ; n_comparisons = N + n_neg
// ---------------------------------------------------------------------------
__global__ __launch_bounds__(1024) void reduce_kernel(
    const float* __restrict__ posP, const float* __restrict__ negP,
    const int* __restrict__ lab, float* __restrict__ out) {
    __shared__ unsigned int hist[4][1024];
    int t = threadIdx.x;
    int w = t >> 6, lane = t & 63;
    for (int i = t; i < 4096; i += 1024) hist[i >> 10][i & 1023] = 0u;
    __syncthreads();
    const int4* lab4 = (const int4*)lab;
    for (int i = t; i < NN / 4; i += 1024) {
        int4 v = lab4[i];
        atomicAdd(&hist[w & 3][v.x & 1023], 1u);
        atomicAdd(&hist[w & 3][v.y & 1023], 1u);
        atomicAdd(&hist[w & 3][v.z & 1023], 1u);
        atomicAdd(&hist[w & 3][v.w & 1023], 1u);
    }
    __syncthreads();

    float ps = 0.f, ns = 0.f;
    unsigned long long sqc = 0u;
    const float4* posP4 = (const float4*)posP;
    for (int i = t; i < NPOSB / 4; i += 1024) {
        float4 v = posP4[i];
        ps += (v.x + v.y) + (v.z + v.w);
    }
    if (t < NBLK) ns = negP[t];
    {
        unsigned long long h = (unsigned long long)hist[0][t & 1023] + hist[1][t & 1023]
                             + hist[2][t & 1023] + hist[3][t & 1023];
        sqc = h * h;
    }

    ps = wave_sum_f(ps);
    ns = wave_sum_f(ns);
    #pragma unroll
    for (int o = 32; o >= 1; o >>= 1) sqc += __shfl_xor(sqc, o);

    __shared__ float sp[16], sn[16];
    __shared__ unsigned long long sc[16];
    if (lane == 0) { sp[w] = ps; sn[w] = ns; sc[w] = sqc; }
    __syncthreads();
    if (t == 0) {
        float pos = 0.f, neg = 0.f;
        unsigned long long s2 = 0;
        #pragma unroll
        for (int i = 0; i < 16; ++i) { pos += sp[i]; neg += sn[i]; s2 += sc[i]; }
        unsigned long long nneg = (unsigned long long)NN * NN - s2;
        float ncomp = (float)((unsigned long long)NN + nneg);
        out[0] = (pos + neg) / ncomp;
    }
}

// ---------------------------------------------------------------------------
// ws layout (bytes):
//   up   @ 0        : 131072  (float2[16384]: {u, label})
//   vcp  @ 131072   : 131072  (float2[16384]: {vc, label})
//   ebf  @ 262144   : 2097152
//   posP @ 2359296  : 16384   (NPOSB floats)
//   negP @ 2375680  : 2048    (NBLK=512 floats)
//   total 2377728
// ---------------------------------------------------------------------------
extern "C" void kernel_launch(void* const* d_in, const int* in_sizes, int n_in,
                              void* d_out, int out_size, void* d_ws, size_t ws_size,
                              hipStream_t stream) {
    const float* emb = (const float*)d_in[0];
    const int* lab   = (const int*)d_in[1];
    const int* pidx  = (const int*)d_in[2];
    float* out = (float*)d_out;
    char* ws = (char*)d_ws;
    float2*         up   = (float2*)(ws);
    float2*         vcp  = (float2*)(ws + 131072);
    __hip_bfloat16* ebf  = (__hip_bfloat16*)(ws + 262144);
    float*          posP = (float*)(ws + 2359296);
    float*          negP = (float*)(ws + 2375680);

    norm_kernel<<<NPOSB, 256, 0, stream>>>(emb, pidx, lab, up, vcp, ebf, posP);
    pair_kernel<<<NBLK, 512, 0, stream>>>((const short*)ebf, up, vcp, negP);
    reduce_kernel<<<1, 1024, 0, stream>>>(posP, negP, lab, out);
}